// Round 6
// baseline (539.606 us; speedup 1.0000x reference)
//
#include <hip/hip_runtime.h>

// EGNN fused layer, MFMA bf16 edge+node kernels, DMA staging throughout.
// R5 evidence: staging-conflict fix worked (conflicts 1.08e8->125K). Edge now
// wait-bound: occupancy 31%, MfmaUtil 8.5%, 13 vmcnt(0)-draining barriers,
// 4 of which waited on 64 outstanding agg-atomic acks. Node path (fp32 VALU,
// <1 block/CU) measured ~170us of the 458 total.
// R6 changes: (1) edge: agg atomics moved to kernel tail (no barrier ever
// drains them) + launch_bounds(256,4) -> 4 blocks/CU. (2) node MLP -> MFMA
// bf16 (same staging pattern; agg converted to bf16 by reusing hconv);
// residual+LayerNorm epilogue stays fp32.

#define H    128
#define ED   48
#define KIN  305   // 2H + ED + 1
#define NTILE 15   // Wm1 x5, Wm2 x2, Wc1 x2, Wn1 x4, Wn2 x2

typedef __attribute__((ext_vector_type(8))) short bf16x8;
typedef __attribute__((ext_vector_type(4))) float f32x4;

__device__ __forceinline__ float silu_f(float v) {
  return v / (1.0f + __expf(-v));
}

__device__ __forceinline__ unsigned short f2bf(float f) {
  unsigned u = __float_as_uint(f);
  return (unsigned short)((u + 0x7FFFu + ((u >> 16) & 1u)) >> 16);
}

__device__ __forceinline__ void gload16(const unsigned short* g, unsigned short* l) {
  __builtin_amdgcn_global_load_lds((const __attribute__((address_space(1))) void*)g,
                                   (__attribute__((address_space(3))) void*)l, 16, 0, 0);
}

// ---- pre-kernel: weights -> pre-swizzled bf16 tiles ----
__global__ void egnn_wconv(const float* __restrict__ Wm1, const float* __restrict__ Wm2,
                           const float* __restrict__ Wc1, const float* __restrict__ Wn1,
                           const float* __restrict__ Wn2, unsigned short* __restrict__ wpre) {
  int c = blockIdx.x * 256 + threadIdx.x;      // global chunk id
  if (c >= NTILE * 1024) return;
  int tile = c >> 10;
  int o    = c & 1023;
  int col  = o >> 3;
  int ck   = (o & 7) ^ (col & 7);
  const float* W; int k0, rows;
  if (tile < 5)       { W = Wm1; k0 = tile * 64;        rows = KIN; }
  else if (tile < 7)  { W = Wm2; k0 = (tile - 5) * 64;  rows = H; }
  else if (tile < 9)  { W = Wc1; k0 = (tile - 7) * 64;  rows = H; }
  else if (tile < 13) { W = Wn1; k0 = (tile - 9) * 64;  rows = 2 * H; }
  else                { W = Wn2; k0 = (tile - 13) * 64; rows = H; }
  unsigned short v[8];
  #pragma unroll
  for (int j = 0; j < 8; ++j) {
    int k = k0 + ck * 8 + j;
    v[j] = (k < rows) ? f2bf(W[(size_t)k * H + col]) : (unsigned short)0;
  }
  *(uint4*)&wpre[(size_t)c * 8] = *(const uint4*)v;
}

// ---- pre-kernel: f32 -> bf16 (8 elems/thread); used for h and agg ----
__global__ void egnn_hconv(const float* __restrict__ src, unsigned short* __restrict__ dst,
                           int total) {
  int i = blockIdx.x * 256 + threadIdx.x;
  if (i >= total) return;
  const float* s = src + (size_t)i * 8;
  float4 f0 = *(const float4*)s;
  float4 f1 = *(const float4*)(s + 4);
  unsigned short v[8] = {f2bf(f0.x), f2bf(f0.y), f2bf(f0.z), f2bf(f0.w),
                         f2bf(f1.x), f2bf(f1.y), f2bf(f1.z), f2bf(f1.w)};
  *(uint4*)&dst[(size_t)i * 8] = *(const uint4*)v;
}

__device__ __forceinline__ void store_chunk(unsigned short* sA, int e, int ck,
                                            float4 f0, float4 f1) {
  unsigned short v[8] = {f2bf(f0.x), f2bf(f0.y), f2bf(f0.z), f2bf(f0.w),
                         f2bf(f1.x), f2bf(f1.y), f2bf(f1.z), f2bf(f1.w)};
  *(uint4*)&sA[e * 64 + ((ck ^ (e & 7)) << 3)] = *(const uint4*)v;
}

__device__ __forceinline__ void mfma_tile(const unsigned short* sA, const unsigned short* sB,
                                          int wv, int lr, int lg, f32x4 (&acc)[8][2]) {
  #pragma unroll
  for (int s = 0; s < 2; ++s) {
    int ck = s * 4 + lg;
    int e0 = wv * 32 + lr, e1 = e0 + 16;
    bf16x8 a0 = *(const bf16x8*)&sA[e0 * 64 + ((ck ^ (e0 & 7)) << 3)];
    bf16x8 a1 = *(const bf16x8*)&sA[e1 * 64 + ((ck ^ (e1 & 7)) << 3)];
    #pragma unroll
    for (int ct = 0; ct < 8; ++ct) {
      int col = ct * 16 + lr;
      bf16x8 b = *(const bf16x8*)&sB[col * 64 + ((ck ^ (col & 7)) << 3)];
      acc[ct][0] = __builtin_amdgcn_mfma_f32_16x16x32_bf16(a0, b, acc[ct][0], 0, 0, 0);
      acc[ct][1] = __builtin_amdgcn_mfma_f32_16x16x32_bf16(a1, b, acc[ct][1], 0, 0, 0);
    }
  }
}

__global__ __launch_bounds__(256, 4)
void egnn_edge_mfma(const float* __restrict__ x,
                    const int* __restrict__ ei, const float* __restrict__ ea,
                    const unsigned short* __restrict__ hbf,
                    const unsigned short* __restrict__ wpre,
                    const float* __restrict__ bm1, const float* __restrict__ bm2,
                    const float* __restrict__ bc1,
                    const float* __restrict__ Wc2, const float* __restrict__ bc2,
                    float* __restrict__ agg, float* __restrict__ cdelta, int E)
{
  __shared__ unsigned short sA[128 * 64];
  __shared__ unsigned short sB[128 * 64];
  __shared__ int   sSrc[128], sDst[128];
  __shared__ float sR[3][128];

  const int t    = threadIdx.x;
  const int lane = t & 63;
  const int wv   = t >> 6;
  const int lr   = lane & 15;
  const int lg   = lane >> 4;
  const int eb   = blockIdx.x * 128;

  if (t < 128) {
    int e  = eb + t;
    int ec = (e < E) ? e : (E - 1);
    int s  = ei[ec];
    int d  = ei[E + ec];
    sSrc[t] = s; sDst[t] = d;
    float rx = x[s * 3 + 0] - x[d * 3 + 0];
    float ry = x[s * 3 + 1] - x[d * 3 + 1];
    float rz = x[s * 3 + 2] - x[d * 3 + 2];
    sR[0][t] = rx; sR[1][t] = ry; sR[2][t] = rz;
  }
  __syncthreads();

  // ---------------- layer 1: z1 = msg_input @ Wm1 + bm1 ----------------
  f32x4 acc1[8][2];
  #pragma unroll
  for (int ct = 0; ct < 8; ++ct) {
    float b = bm1[ct * 16 + lr];
    #pragma unroll
    for (int rt = 0; rt < 2; ++rt) {
      acc1[ct][rt][0] = b; acc1[ct][rt][1] = b;
      acc1[ct][rt][2] = b; acc1[ct][rt][3] = b;
    }
  }

  for (int ch = 0; ch < 4; ++ch) {
    __syncthreads();
    {
      const unsigned short* wsrc = wpre + (size_t)ch * 8192 + wv * 2048 + lane * 8;
      unsigned short* bdst = &sB[wv * 2048];
      #pragma unroll
      for (int i = 0; i < 4; ++i)
        gload16(wsrc + i * 512, bdst + i * 512);
    }
    #pragma unroll
    for (int i = 0; i < 4; ++i) {
      int e   = wv * 32 + i * 8 + (lane >> 3);
      int ckp = lane & 7;
      int row = (ch < 2) ? sSrc[e] : sDst[e];
      const unsigned short* asrc =
          hbf + (size_t)row * 128 + (ch & 1) * 64 + ((ckp ^ (e & 7)) << 3);
      gload16(asrc, &sA[(size_t)(wv * 32 + i * 8) * 64]);
    }
    __syncthreads();
    mfma_tile(sA, sB, wv, lr, lg, acc1);
  }

  // ea + d2 chunk (k 256..319)
  {
    __syncthreads();
    const int se = t >> 1;
    const int sh = t & 1;
    int ecl = (eb + se < E) ? (eb + se) : (E - 1);
    if (sh == 0) {
      const float* __restrict__ ep = &ea[(size_t)ecl * ED];
      #pragma unroll
      for (int c = 0; c < 4; ++c) {
        float4 f0 = *(const float4*)&ep[c * 8];
        float4 f1 = *(const float4*)&ep[c * 8 + 4];
        store_chunk(sA, se, c, f0, f1);
      }
    } else {
      const float* __restrict__ ep = &ea[(size_t)ecl * ED + 32];
      float4 f0 = *(const float4*)&ep[0];
      float4 f1 = *(const float4*)&ep[4];
      store_chunk(sA, se, 4, f0, f1);
      f0 = *(const float4*)&ep[8];
      f1 = *(const float4*)&ep[12];
      store_chunk(sA, se, 5, f0, f1);
      float rx = sR[0][se], ry = sR[1][se], rz = sR[2][se];
      float d2 = rx * rx + ry * ry + rz * rz;
      store_chunk(sA, se, 6, make_float4(d2, 0.f, 0.f, 0.f),
                  make_float4(0.f, 0.f, 0.f, 0.f));
      store_chunk(sA, se, 7, make_float4(0.f, 0.f, 0.f, 0.f),
                  make_float4(0.f, 0.f, 0.f, 0.f));
    }
    const unsigned short* wsrc = wpre + (size_t)4 * 8192 + wv * 2048 + lane * 8;
    unsigned short* bdst = &sB[wv * 2048];
    #pragma unroll
    for (int i = 0; i < 4; ++i)
      gload16(wsrc + i * 512, bdst + i * 512);
    __syncthreads();
    mfma_tile(sA, sB, wv, lr, lg, acc1);
  }

  // ---------------- layer 2: msg = silu(z1) @ Wm2 + bm2 ----------------
  f32x4 acc2[8][2];
  #pragma unroll
  for (int ct = 0; ct < 8; ++ct) {
    float b = bm2[ct * 16 + lr];
    #pragma unroll
    for (int rt = 0; rt < 2; ++rt) {
      acc2[ct][rt][0] = b; acc2[ct][rt][1] = b;
      acc2[ct][rt][2] = b; acc2[ct][rt][3] = b;
    }
  }

  for (int p = 0; p < 2; ++p) {
    __syncthreads();
    #pragma unroll
    for (int ci = 0; ci < 4; ++ci) {
      int ct = p * 4 + ci;
      int kl = ci * 16 + lr;
      int ck = kl >> 3;
      #pragma unroll
      for (int rt = 0; rt < 2; ++rt) {
        #pragma unroll
        for (int r = 0; r < 4; ++r) {
          int e = wv * 32 + rt * 16 + lg * 4 + r;
          sA[e * 64 + ((ck ^ (e & 7)) << 3) + (kl & 7)] = f2bf(silu_f(acc1[ct][rt][r]));
        }
      }
    }
    const unsigned short* wsrc = wpre + (size_t)(5 + p) * 8192 + wv * 2048 + lane * 8;
    unsigned short* bdst = &sB[wv * 2048];
    #pragma unroll
    for (int i = 0; i < 4; ++i)
      gload16(wsrc + i * 512, bdst + i * 512);
    __syncthreads();
    mfma_tile(sA, sB, wv, lr, lg, acc2);
  }

  // ---------------- layer 3 gate: z3 = msg @ Wc1 + bc1 ----------------
  // (agg atomics DEFERRED to kernel tail so no phase barrier drains them)
  f32x4 acc3[8][2];
  #pragma unroll
  for (int ct = 0; ct < 8; ++ct) {
    float b = bc1[ct * 16 + lr];
    #pragma unroll
    for (int rt = 0; rt < 2; ++rt) {
      acc3[ct][rt][0] = b; acc3[ct][rt][1] = b;
      acc3[ct][rt][2] = b; acc3[ct][rt][3] = b;
    }
  }

  for (int p = 0; p < 2; ++p) {
    __syncthreads();
    #pragma unroll
    for (int ci = 0; ci < 4; ++ci) {
      int ct = p * 4 + ci;
      int kl = ci * 16 + lr;
      int ck = kl >> 3;
      #pragma unroll
      for (int rt = 0; rt < 2; ++rt) {
        #pragma unroll
        for (int r = 0; r < 4; ++r) {
          int e = wv * 32 + rt * 16 + lg * 4 + r;
          sA[e * 64 + ((ck ^ (e & 7)) << 3) + (kl & 7)] = f2bf(acc2[ct][rt][r]);
        }
      }
    }
    const unsigned short* wsrc = wpre + (size_t)(7 + p) * 8192 + wv * 2048 + lane * 8;
    unsigned short* bdst = &sB[wv * 2048];
    #pragma unroll
    for (int i = 0; i < 4; ++i)
      gload16(wsrc + i * 512, bdst + i * 512);
    __syncthreads();
    mfma_tile(sA, sB, wv, lr, lg, acc3);
  }

  // w = clip(silu(z3) . Wc2 + bc2, -1, 1); coord_delta[dst] += w * r_ij
  float wsum[2][4];
  #pragma unroll
  for (int rt = 0; rt < 2; ++rt)
    #pragma unroll
    for (int r = 0; r < 4; ++r) wsum[rt][r] = 0.f;

  #pragma unroll
  for (int ct = 0; ct < 8; ++ct) {
    float wc = Wc2[ct * 16 + lr];
    #pragma unroll
    for (int rt = 0; rt < 2; ++rt)
      #pragma unroll
      for (int r = 0; r < 4; ++r)
        wsum[rt][r] = fmaf(silu_f(acc3[ct][rt][r]), wc, wsum[rt][r]);
  }
  const float bc2v = bc2[0];
  #pragma unroll
  for (int rt = 0; rt < 2; ++rt) {
    #pragma unroll
    for (int r = 0; r < 4; ++r) {
      float s = wsum[rt][r];
      s += __shfl_xor(s, 1); s += __shfl_xor(s, 2);
      s += __shfl_xor(s, 4); s += __shfl_xor(s, 8);
      int el = wv * 32 + rt * 16 + lg * 4 + r;
      if (lr == 0 && eb + el < E) {
        float wval = fminf(fmaxf(s + bc2v, -1.0f), 1.0f);
        int d = sDst[el];
        atomicAdd(&cdelta[(size_t)d * 3 + 0], wval * sR[0][el]);
        atomicAdd(&cdelta[(size_t)d * 3 + 1], wval * sR[1][el]);
        atomicAdd(&cdelta[(size_t)d * 3 + 2], wval * sR[2][el]);
      }
    }
  }

  // ---- agg[dst] += msg (fp32 atomics, fire-and-forget at kernel tail)
  #pragma unroll
  for (int ct = 0; ct < 8; ++ct) {
    int col = ct * 16 + lr;
    #pragma unroll
    for (int rt = 0; rt < 2; ++rt) {
      #pragma unroll
      for (int r = 0; r < 4; ++r) {
        int el = wv * 32 + rt * 16 + lg * 4 + r;
        if (eb + el < E)
          atomicAdd(&agg[(size_t)sDst[el] * H + col], acc2[ct][rt][r]);
      }
    }
  }
}

// ---------------- node kernel: MFMA bf16 MLP + fp32 residual/LN ----------------
__global__ __launch_bounds__(256)
void egnn_node_mfma(const float* __restrict__ x, const float* __restrict__ h,
                    const unsigned short* __restrict__ hbf,
                    const unsigned short* __restrict__ aggbf,
                    const unsigned short* __restrict__ wpre,
                    const float* __restrict__ bn1, const float* __restrict__ bn2,
                    const float* __restrict__ gamma, const float* __restrict__ beta,
                    const float* __restrict__ cdelta,
                    float* __restrict__ out_x, float* __restrict__ out_h, int N)
{
  __shared__ unsigned short sA[128 * 64];
  __shared__ unsigned short sB[128 * 64];

  const int t    = threadIdx.x;
  const int lane = t & 63;
  const int wv   = t >> 6;
  const int lr   = lane & 15;
  const int lg   = lane >> 4;
  const int nb   = blockIdx.x * 128;

  // layer 1: concat[h,agg] @ Wn1 + bn1   (K=256, tiles 9..12)
  f32x4 acc1[8][2];
  #pragma unroll
  for (int ct = 0; ct < 8; ++ct) {
    float b = bn1[ct * 16 + lr];
    #pragma unroll
    for (int rt = 0; rt < 2; ++rt) {
      acc1[ct][rt][0] = b; acc1[ct][rt][1] = b;
      acc1[ct][rt][2] = b; acc1[ct][rt][3] = b;
    }
  }

  for (int ch = 0; ch < 4; ++ch) {
    __syncthreads();
    {
      const unsigned short* wsrc = wpre + (size_t)(9 + ch) * 8192 + wv * 2048 + lane * 8;
      unsigned short* bdst = &sB[wv * 2048];
      #pragma unroll
      for (int i = 0; i < 4; ++i)
        gload16(wsrc + i * 512, bdst + i * 512);
    }
    const unsigned short* abase = (ch < 2) ? hbf : aggbf;
    #pragma unroll
    for (int i = 0; i < 4; ++i) {
      int e   = wv * 32 + i * 8 + (lane >> 3);
      int ckp = lane & 7;
      int n   = nb + e; if (n >= N) n = N - 1;
      const unsigned short* asrc =
          abase + (size_t)n * 128 + (ch & 1) * 64 + ((ckp ^ (e & 7)) << 3);
      gload16(asrc, &sA[(size_t)(wv * 32 + i * 8) * 64]);
    }
    __syncthreads();
    mfma_tile(sA, sB, wv, lr, lg, acc1);
  }

  // layer 2: silu @ Wn2 + bn2   (tiles 13..14)
  f32x4 acc2[8][2];
  #pragma unroll
  for (int ct = 0; ct < 8; ++ct) {
    float b = bn2[ct * 16 + lr];
    #pragma unroll
    for (int rt = 0; rt < 2; ++rt) {
      acc2[ct][rt][0] = b; acc2[ct][rt][1] = b;
      acc2[ct][rt][2] = b; acc2[ct][rt][3] = b;
    }
  }

  for (int p = 0; p < 2; ++p) {
    __syncthreads();
    #pragma unroll
    for (int ci = 0; ci < 4; ++ci) {
      int ct = p * 4 + ci;
      int kl = ci * 16 + lr;
      int ck = kl >> 3;
      #pragma unroll
      for (int rt = 0; rt < 2; ++rt) {
        #pragma unroll
        for (int r = 0; r < 4; ++r) {
          int e = wv * 32 + rt * 16 + lg * 4 + r;
          sA[e * 64 + ((ck ^ (e & 7)) << 3) + (kl & 7)] = f2bf(silu_f(acc1[ct][rt][r]));
        }
      }
    }
    const unsigned short* wsrc = wpre + (size_t)(13 + p) * 8192 + wv * 2048 + lane * 8;
    unsigned short* bdst = &sB[wv * 2048];
    #pragma unroll
    for (int i = 0; i < 4; ++i)
      gload16(wsrc + i * 512, bdst + i * 512);
    __syncthreads();
    mfma_tile(sA, sB, wv, lr, lg, acc2);
  }

  // residual + LayerNorm + store h_new (fp32)
  float gma[8], bta[8];
  #pragma unroll
  for (int ct = 0; ct < 8; ++ct) {
    gma[ct] = gamma[ct * 16 + lr];
    bta[ct] = beta[ct * 16 + lr];
  }
  #pragma unroll
  for (int rt = 0; rt < 2; ++rt) {
    #pragma unroll
    for (int r = 0; r < 4; ++r) {
      int nl = wv * 32 + rt * 16 + lg * 4 + r;
      int n  = nb + nl;
      bool ok = (n < N);
      float v[8];
      #pragma unroll
      for (int ct = 0; ct < 8; ++ct) {
        float hv = ok ? h[(size_t)n * H + ct * 16 + lr] : 0.f;
        v[ct] = acc2[ct][rt][r] + hv;
      }
      float s = 0.f, sq = 0.f;
      #pragma unroll
      for (int ct = 0; ct < 8; ++ct) { s += v[ct]; sq += v[ct] * v[ct]; }
      #pragma unroll
      for (int m = 1; m < 16; m <<= 1) { s += __shfl_xor(s, m); sq += __shfl_xor(sq, m); }
      float mu  = s * (1.0f / 128.0f);
      float var = sq * (1.0f / 128.0f) - mu * mu;
      float rs  = rsqrtf(var + 1e-5f);
      if (ok) {
        #pragma unroll
        for (int ct = 0; ct < 8; ++ct)
          out_h[(size_t)n * H + ct * 16 + lr] = (v[ct] - mu) * rs * gma[ct] + bta[ct];
      }
    }
  }

  // x_new = x + coord_delta
  if (t < 128) {
    int n = nb + t;
    if (n < N) {
      #pragma unroll
      for (int c = 0; c < 3; ++c)
        out_x[(size_t)n * 3 + c] = x[(size_t)n * 3 + c] + cdelta[(size_t)n * 3 + c];
    }
  }
}

extern "C" void kernel_launch(void* const* d_in, const int* in_sizes, int n_in,
                              void* d_out, int out_size, void* d_ws, size_t ws_size,
                              hipStream_t stream) {
  const float* x     = (const float*)d_in[0];
  const float* h     = (const float*)d_in[1];
  const int*   ei    = (const int*)d_in[2];
  const float* ea    = (const float*)d_in[3];
  const float* Wm1   = (const float*)d_in[4];
  const float* bm1   = (const float*)d_in[5];
  const float* Wm2   = (const float*)d_in[6];
  const float* bm2   = (const float*)d_in[7];
  const float* Wn1   = (const float*)d_in[8];
  const float* bn1   = (const float*)d_in[9];
  const float* Wn2   = (const float*)d_in[10];
  const float* bn2   = (const float*)d_in[11];
  const float* Wc1   = (const float*)d_in[12];
  const float* bc1   = (const float*)d_in[13];
  const float* Wc2   = (const float*)d_in[14];
  const float* bc2   = (const float*)d_in[15];
  const float* gamma = (const float*)d_in[16];
  const float* beta  = (const float*)d_in[17];

  const int N = in_sizes[0] / 3;
  const int E = in_sizes[2] / 2;

  float* agg    = (float*)d_ws;                                     // N*H f32
  float* cdelta = agg + (size_t)N * H;                              // N*3 f32
  unsigned short* hbf   = (unsigned short*)(cdelta + (size_t)N * 3);// N*H bf16
  unsigned short* aggbf = hbf + (size_t)N * H;                      // N*H bf16
  unsigned short* wpre  = aggbf + (size_t)N * H;                    // NTILE*8192 bf16
  float* out_x  = (float*)d_out;
  float* out_h  = out_x + (size_t)N * 3;

  hipMemsetAsync(d_ws, 0, (size_t)(N * H + N * 3) * sizeof(float), stream);

  egnn_wconv<<<(NTILE * 1024 + 255) / 256, 256, 0, stream>>>(Wm1, Wm2, Wc1, Wn1, Wn2, wpre);
  egnn_hconv<<<(N * 16 + 255) / 256, 256, 0, stream>>>(h, hbf, N * 16);

  const int eblocks = (E + 127) / 128;
  egnn_edge_mfma<<<eblocks, 256, 0, stream>>>(
      x, ei, ea, hbf, wpre, bm1, bm2, bc1, Wc2, bc2, agg, cdelta, E);

  egnn_hconv<<<(N * 16 + 255) / 256, 256, 0, stream>>>(agg, aggbf, N * 16);

  const int nblocks = (N + 127) / 128;
  egnn_node_mfma<<<nblocks, 256, 0, stream>>>(
      x, h, hbf, aggbf, wpre, bn1, bn2, gamma, beta, cdelta, out_x, out_h, N);
}

// Round 10
// 464.120 us; speedup vs baseline: 1.1626x; 1.1626x over previous
//
#include <hip/hip_runtime.h>

// EGNN fused layer, MFMA bf16 edge+node kernels, DMA staging throughout.
// R6 post-mortem: launch_bounds(256,4) capped regs at 128/thread -> ~40-reg
// scratch spill; concurrent scratch (42MB) > L2 -> +589MB HBM/dispatch, edge
// 288->435us. R7: revert to (256,3) (84 VGPR + AGPR fits 170/thread, no
// spill), KEEP tail-deferred agg atomics (no phase barrier drains their acks).
// Node MLP stays MFMA bf16 (R6: non-edge time 170->105us).

#define H    128
#define ED   48
#define KIN  305   // 2H + ED + 1
#define NTILE 15   // Wm1 x5, Wm2 x2, Wc1 x2, Wn1 x4, Wn2 x2

typedef __attribute__((ext_vector_type(8))) short bf16x8;
typedef __attribute__((ext_vector_type(4))) float f32x4;

__device__ __forceinline__ float silu_f(float v) {
  return v / (1.0f + __expf(-v));
}

__device__ __forceinline__ unsigned short f2bf(float f) {
  unsigned u = __float_as_uint(f);
  return (unsigned short)((u + 0x7FFFu + ((u >> 16) & 1u)) >> 16);
}

__device__ __forceinline__ void gload16(const unsigned short* g, unsigned short* l) {
  __builtin_amdgcn_global_load_lds((const __attribute__((address_space(1))) void*)g,
                                   (__attribute__((address_space(3))) void*)l, 16, 0, 0);
}

// ---- pre-kernel: weights -> pre-swizzled bf16 tiles ----
__global__ void egnn_wconv(const float* __restrict__ Wm1, const float* __restrict__ Wm2,
                           const float* __restrict__ Wc1, const float* __restrict__ Wn1,
                           const float* __restrict__ Wn2, unsigned short* __restrict__ wpre) {
  int c = blockIdx.x * 256 + threadIdx.x;      // global chunk id
  if (c >= NTILE * 1024) return;
  int tile = c >> 10;
  int o    = c & 1023;
  int col  = o >> 3;
  int ck   = (o & 7) ^ (col & 7);
  const float* W; int k0, rows;
  if (tile < 5)       { W = Wm1; k0 = tile * 64;        rows = KIN; }
  else if (tile < 7)  { W = Wm2; k0 = (tile - 5) * 64;  rows = H; }
  else if (tile < 9)  { W = Wc1; k0 = (tile - 7) * 64;  rows = H; }
  else if (tile < 13) { W = Wn1; k0 = (tile - 9) * 64;  rows = 2 * H; }
  else                { W = Wn2; k0 = (tile - 13) * 64; rows = H; }
  unsigned short v[8];
  #pragma unroll
  for (int j = 0; j < 8; ++j) {
    int k = k0 + ck * 8 + j;
    v[j] = (k < rows) ? f2bf(W[(size_t)k * H + col]) : (unsigned short)0;
  }
  *(uint4*)&wpre[(size_t)c * 8] = *(const uint4*)v;
}

// ---- pre-kernel: f32 -> bf16 (8 elems/thread); used for h and agg ----
__global__ void egnn_hconv(const float* __restrict__ src, unsigned short* __restrict__ dst,
                           int total) {
  int i = blockIdx.x * 256 + threadIdx.x;
  if (i >= total) return;
  const float* s = src + (size_t)i * 8;
  float4 f0 = *(const float4*)s;
  float4 f1 = *(const float4*)(s + 4);
  unsigned short v[8] = {f2bf(f0.x), f2bf(f0.y), f2bf(f0.z), f2bf(f0.w),
                         f2bf(f1.x), f2bf(f1.y), f2bf(f1.z), f2bf(f1.w)};
  *(uint4*)&dst[(size_t)i * 8] = *(const uint4*)v;
}

__device__ __forceinline__ void store_chunk(unsigned short* sA, int e, int ck,
                                            float4 f0, float4 f1) {
  unsigned short v[8] = {f2bf(f0.x), f2bf(f0.y), f2bf(f0.z), f2bf(f0.w),
                         f2bf(f1.x), f2bf(f1.y), f2bf(f1.z), f2bf(f1.w)};
  *(uint4*)&sA[e * 64 + ((ck ^ (e & 7)) << 3)] = *(const uint4*)v;
}

__device__ __forceinline__ void mfma_tile(const unsigned short* sA, const unsigned short* sB,
                                          int wv, int lr, int lg, f32x4 (&acc)[8][2]) {
  #pragma unroll
  for (int s = 0; s < 2; ++s) {
    int ck = s * 4 + lg;
    int e0 = wv * 32 + lr, e1 = e0 + 16;
    bf16x8 a0 = *(const bf16x8*)&sA[e0 * 64 + ((ck ^ (e0 & 7)) << 3)];
    bf16x8 a1 = *(const bf16x8*)&sA[e1 * 64 + ((ck ^ (e1 & 7)) << 3)];
    #pragma unroll
    for (int ct = 0; ct < 8; ++ct) {
      int col = ct * 16 + lr;
      bf16x8 b = *(const bf16x8*)&sB[col * 64 + ((ck ^ (col & 7)) << 3)];
      acc[ct][0] = __builtin_amdgcn_mfma_f32_16x16x32_bf16(a0, b, acc[ct][0], 0, 0, 0);
      acc[ct][1] = __builtin_amdgcn_mfma_f32_16x16x32_bf16(a1, b, acc[ct][1], 0, 0, 0);
    }
  }
}

__global__ __launch_bounds__(256, 3)
void egnn_edge_mfma(const float* __restrict__ x,
                    const int* __restrict__ ei, const float* __restrict__ ea,
                    const unsigned short* __restrict__ hbf,
                    const unsigned short* __restrict__ wpre,
                    const float* __restrict__ bm1, const float* __restrict__ bm2,
                    const float* __restrict__ bc1,
                    const float* __restrict__ Wc2, const float* __restrict__ bc2,
                    float* __restrict__ agg, float* __restrict__ cdelta, int E)
{
  __shared__ unsigned short sA[128 * 64];
  __shared__ unsigned short sB[128 * 64];
  __shared__ int   sSrc[128], sDst[128];
  __shared__ float sR[3][128];

  const int t    = threadIdx.x;
  const int lane = t & 63;
  const int wv   = t >> 6;
  const int lr   = lane & 15;
  const int lg   = lane >> 4;
  const int eb   = blockIdx.x * 128;

  if (t < 128) {
    int e  = eb + t;
    int ec = (e < E) ? e : (E - 1);
    int s  = ei[ec];
    int d  = ei[E + ec];
    sSrc[t] = s; sDst[t] = d;
    float rx = x[s * 3 + 0] - x[d * 3 + 0];
    float ry = x[s * 3 + 1] - x[d * 3 + 1];
    float rz = x[s * 3 + 2] - x[d * 3 + 2];
    sR[0][t] = rx; sR[1][t] = ry; sR[2][t] = rz;
  }
  __syncthreads();

  // ---------------- layer 1: z1 = msg_input @ Wm1 + bm1 ----------------
  f32x4 acc1[8][2];
  #pragma unroll
  for (int ct = 0; ct < 8; ++ct) {
    float b = bm1[ct * 16 + lr];
    #pragma unroll
    for (int rt = 0; rt < 2; ++rt) {
      acc1[ct][rt][0] = b; acc1[ct][rt][1] = b;
      acc1[ct][rt][2] = b; acc1[ct][rt][3] = b;
    }
  }

  for (int ch = 0; ch < 4; ++ch) {
    __syncthreads();
    {
      const unsigned short* wsrc = wpre + (size_t)ch * 8192 + wv * 2048 + lane * 8;
      unsigned short* bdst = &sB[wv * 2048];
      #pragma unroll
      for (int i = 0; i < 4; ++i)
        gload16(wsrc + i * 512, bdst + i * 512);
    }
    #pragma unroll
    for (int i = 0; i < 4; ++i) {
      int e   = wv * 32 + i * 8 + (lane >> 3);
      int ckp = lane & 7;
      int row = (ch < 2) ? sSrc[e] : sDst[e];
      const unsigned short* asrc =
          hbf + (size_t)row * 128 + (ch & 1) * 64 + ((ckp ^ (e & 7)) << 3);
      gload16(asrc, &sA[(size_t)(wv * 32 + i * 8) * 64]);
    }
    __syncthreads();
    mfma_tile(sA, sB, wv, lr, lg, acc1);
  }

  // ea + d2 chunk (k 256..319)
  {
    __syncthreads();
    const int se = t >> 1;
    const int sh = t & 1;
    int ecl = (eb + se < E) ? (eb + se) : (E - 1);
    if (sh == 0) {
      const float* __restrict__ ep = &ea[(size_t)ecl * ED];
      #pragma unroll
      for (int c = 0; c < 4; ++c) {
        float4 f0 = *(const float4*)&ep[c * 8];
        float4 f1 = *(const float4*)&ep[c * 8 + 4];
        store_chunk(sA, se, c, f0, f1);
      }
    } else {
      const float* __restrict__ ep = &ea[(size_t)ecl * ED + 32];
      float4 f0 = *(const float4*)&ep[0];
      float4 f1 = *(const float4*)&ep[4];
      store_chunk(sA, se, 4, f0, f1);
      f0 = *(const float4*)&ep[8];
      f1 = *(const float4*)&ep[12];
      store_chunk(sA, se, 5, f0, f1);
      float rx = sR[0][se], ry = sR[1][se], rz = sR[2][se];
      float d2 = rx * rx + ry * ry + rz * rz;
      store_chunk(sA, se, 6, make_float4(d2, 0.f, 0.f, 0.f),
                  make_float4(0.f, 0.f, 0.f, 0.f));
      store_chunk(sA, se, 7, make_float4(0.f, 0.f, 0.f, 0.f),
                  make_float4(0.f, 0.f, 0.f, 0.f));
    }
    const unsigned short* wsrc = wpre + (size_t)4 * 8192 + wv * 2048 + lane * 8;
    unsigned short* bdst = &sB[wv * 2048];
    #pragma unroll
    for (int i = 0; i < 4; ++i)
      gload16(wsrc + i * 512, bdst + i * 512);
    __syncthreads();
    mfma_tile(sA, sB, wv, lr, lg, acc1);
  }

  // ---------------- layer 2: msg = silu(z1) @ Wm2 + bm2 ----------------
  f32x4 acc2[8][2];
  #pragma unroll
  for (int ct = 0; ct < 8; ++ct) {
    float b = bm2[ct * 16 + lr];
    #pragma unroll
    for (int rt = 0; rt < 2; ++rt) {
      acc2[ct][rt][0] = b; acc2[ct][rt][1] = b;
      acc2[ct][rt][2] = b; acc2[ct][rt][3] = b;
    }
  }

  for (int p = 0; p < 2; ++p) {
    __syncthreads();
    #pragma unroll
    for (int ci = 0; ci < 4; ++ci) {
      int ct = p * 4 + ci;
      int kl = ci * 16 + lr;
      int ck = kl >> 3;
      #pragma unroll
      for (int rt = 0; rt < 2; ++rt) {
        #pragma unroll
        for (int r = 0; r < 4; ++r) {
          int e = wv * 32 + rt * 16 + lg * 4 + r;
          sA[e * 64 + ((ck ^ (e & 7)) << 3) + (kl & 7)] = f2bf(silu_f(acc1[ct][rt][r]));
        }
      }
    }
    const unsigned short* wsrc = wpre + (size_t)(5 + p) * 8192 + wv * 2048 + lane * 8;
    unsigned short* bdst = &sB[wv * 2048];
    #pragma unroll
    for (int i = 0; i < 4; ++i)
      gload16(wsrc + i * 512, bdst + i * 512);
    __syncthreads();
    mfma_tile(sA, sB, wv, lr, lg, acc2);
  }

  // ---------------- layer 3 gate: z3 = msg @ Wc1 + bc1 ----------------
  // (agg atomics DEFERRED to kernel tail so no phase barrier drains them)
  f32x4 acc3[8][2];
  #pragma unroll
  for (int ct = 0; ct < 8; ++ct) {
    float b = bc1[ct * 16 + lr];
    #pragma unroll
    for (int rt = 0; rt < 2; ++rt) {
      acc3[ct][rt][0] = b; acc3[ct][rt][1] = b;
      acc3[ct][rt][2] = b; acc3[ct][rt][3] = b;
    }
  }

  for (int p = 0; p < 2; ++p) {
    __syncthreads();
    #pragma unroll
    for (int ci = 0; ci < 4; ++ci) {
      int ct = p * 4 + ci;
      int kl = ci * 16 + lr;
      int ck = kl >> 3;
      #pragma unroll
      for (int rt = 0; rt < 2; ++rt) {
        #pragma unroll
        for (int r = 0; r < 4; ++r) {
          int e = wv * 32 + rt * 16 + lg * 4 + r;
          sA[e * 64 + ((ck ^ (e & 7)) << 3) + (kl & 7)] = f2bf(acc2[ct][rt][r]);
        }
      }
    }
    const unsigned short* wsrc = wpre + (size_t)(7 + p) * 8192 + wv * 2048 + lane * 8;
    unsigned short* bdst = &sB[wv * 2048];
    #pragma unroll
    for (int i = 0; i < 4; ++i)
      gload16(wsrc + i * 512, bdst + i * 512);
    __syncthreads();
    mfma_tile(sA, sB, wv, lr, lg, acc3);
  }

  // w = clip(silu(z3) . Wc2 + bc2, -1, 1); coord_delta[dst] += w * r_ij
  float wsum[2][4];
  #pragma unroll
  for (int rt = 0; rt < 2; ++rt)
    #pragma unroll
    for (int r = 0; r < 4; ++r) wsum[rt][r] = 0.f;

  #pragma unroll
  for (int ct = 0; ct < 8; ++ct) {
    float wc = Wc2[ct * 16 + lr];
    #pragma unroll
    for (int rt = 0; rt < 2; ++rt)
      #pragma unroll
      for (int r = 0; r < 4; ++r)
        wsum[rt][r] = fmaf(silu_f(acc3[ct][rt][r]), wc, wsum[rt][r]);
  }
  const float bc2v = bc2[0];
  #pragma unroll
  for (int rt = 0; rt < 2; ++rt) {
    #pragma unroll
    for (int r = 0; r < 4; ++r) {
      float s = wsum[rt][r];
      s += __shfl_xor(s, 1); s += __shfl_xor(s, 2);
      s += __shfl_xor(s, 4); s += __shfl_xor(s, 8);
      int el = wv * 32 + rt * 16 + lg * 4 + r;
      if (lr == 0 && eb + el < E) {
        float wval = fminf(fmaxf(s + bc2v, -1.0f), 1.0f);
        int d = sDst[el];
        atomicAdd(&cdelta[(size_t)d * 3 + 0], wval * sR[0][el]);
        atomicAdd(&cdelta[(size_t)d * 3 + 1], wval * sR[1][el]);
        atomicAdd(&cdelta[(size_t)d * 3 + 2], wval * sR[2][el]);
      }
    }
  }

  // ---- agg[dst] += msg (fp32 atomics, fire-and-forget at kernel tail)
  #pragma unroll
  for (int ct = 0; ct < 8; ++ct) {
    int col = ct * 16 + lr;
    #pragma unroll
    for (int rt = 0; rt < 2; ++rt) {
      #pragma unroll
      for (int r = 0; r < 4; ++r) {
        int el = wv * 32 + rt * 16 + lg * 4 + r;
        if (eb + el < E)
          atomicAdd(&agg[(size_t)sDst[el] * H + col], acc2[ct][rt][r]);
      }
    }
  }
}

// ---------------- node kernel: MFMA bf16 MLP + fp32 residual/LN ----------------
__global__ __launch_bounds__(256)
void egnn_node_mfma(const float* __restrict__ x, const float* __restrict__ h,
                    const unsigned short* __restrict__ hbf,
                    const unsigned short* __restrict__ aggbf,
                    const unsigned short* __restrict__ wpre,
                    const float* __restrict__ bn1, const float* __restrict__ bn2,
                    const float* __restrict__ gamma, const float* __restrict__ beta,
                    const float* __restrict__ cdelta,
                    float* __restrict__ out_x, float* __restrict__ out_h, int N)
{
  __shared__ unsigned short sA[128 * 64];
  __shared__ unsigned short sB[128 * 64];

  const int t    = threadIdx.x;
  const int lane = t & 63;
  const int wv   = t >> 6;
  const int lr   = lane & 15;
  const int lg   = lane >> 4;
  const int nb   = blockIdx.x * 128;

  // layer 1: concat[h,agg] @ Wn1 + bn1   (K=256, tiles 9..12)
  f32x4 acc1[8][2];
  #pragma unroll
  for (int ct = 0; ct < 8; ++ct) {
    float b = bn1[ct * 16 + lr];
    #pragma unroll
    for (int rt = 0; rt < 2; ++rt) {
      acc1[ct][rt][0] = b; acc1[ct][rt][1] = b;
      acc1[ct][rt][2] = b; acc1[ct][rt][3] = b;
    }
  }

  for (int ch = 0; ch < 4; ++ch) {
    __syncthreads();
    {
      const unsigned short* wsrc = wpre + (size_t)(9 + ch) * 8192 + wv * 2048 + lane * 8;
      unsigned short* bdst = &sB[wv * 2048];
      #pragma unroll
      for (int i = 0; i < 4; ++i)
        gload16(wsrc + i * 512, bdst + i * 512);
    }
    const unsigned short* abase = (ch < 2) ? hbf : aggbf;
    #pragma unroll
    for (int i = 0; i < 4; ++i) {
      int e   = wv * 32 + i * 8 + (lane >> 3);
      int ckp = lane & 7;
      int n   = nb + e; if (n >= N) n = N - 1;
      const unsigned short* asrc =
          abase + (size_t)n * 128 + (ch & 1) * 64 + ((ckp ^ (e & 7)) << 3);
      gload16(asrc, &sA[(size_t)(wv * 32 + i * 8) * 64]);
    }
    __syncthreads();
    mfma_tile(sA, sB, wv, lr, lg, acc1);
  }

  // layer 2: silu @ Wn2 + bn2   (tiles 13..14)
  f32x4 acc2[8][2];
  #pragma unroll
  for (int ct = 0; ct < 8; ++ct) {
    float b = bn2[ct * 16 + lr];
    #pragma unroll
    for (int rt = 0; rt < 2; ++rt) {
      acc2[ct][rt][0] = b; acc2[ct][rt][1] = b;
      acc2[ct][rt][2] = b; acc2[ct][rt][3] = b;
    }
  }

  for (int p = 0; p < 2; ++p) {
    __syncthreads();
    #pragma unroll
    for (int ci = 0; ci < 4; ++ci) {
      int ct = p * 4 + ci;
      int kl = ci * 16 + lr;
      int ck = kl >> 3;
      #pragma unroll
      for (int rt = 0; rt < 2; ++rt) {
        #pragma unroll
        for (int r = 0; r < 4; ++r) {
          int e = wv * 32 + rt * 16 + lg * 4 + r;
          sA[e * 64 + ((ck ^ (e & 7)) << 3) + (kl & 7)] = f2bf(silu_f(acc1[ct][rt][r]));
        }
      }
    }
    const unsigned short* wsrc = wpre + (size_t)(13 + p) * 8192 + wv * 2048 + lane * 8;
    unsigned short* bdst = &sB[wv * 2048];
    #pragma unroll
    for (int i = 0; i < 4; ++i)
      gload16(wsrc + i * 512, bdst + i * 512);
    __syncthreads();
    mfma_tile(sA, sB, wv, lr, lg, acc2);
  }

  // residual + LayerNorm + store h_new (fp32)
  float gma[8], bta[8];
  #pragma unroll
  for (int ct = 0; ct < 8; ++ct) {
    gma[ct] = gamma[ct * 16 + lr];
    bta[ct] = beta[ct * 16 + lr];
  }
  #pragma unroll
  for (int rt = 0; rt < 2; ++rt) {
    #pragma unroll
    for (int r = 0; r < 4; ++r) {
      int nl = wv * 32 + rt * 16 + lg * 4 + r;
      int n  = nb + nl;
      bool ok = (n < N);
      float v[8];
      #pragma unroll
      for (int ct = 0; ct < 8; ++ct) {
        float hv = ok ? h[(size_t)n * H + ct * 16 + lr] : 0.f;
        v[ct] = acc2[ct][rt][r] + hv;
      }
      float s = 0.f, sq = 0.f;
      #pragma unroll
      for (int ct = 0; ct < 8; ++ct) { s += v[ct]; sq += v[ct] * v[ct]; }
      #pragma unroll
      for (int m = 1; m < 16; m <<= 1) { s += __shfl_xor(s, m); sq += __shfl_xor(sq, m); }
      float mu  = s * (1.0f / 128.0f);
      float var = sq * (1.0f / 128.0f) - mu * mu;
      float rs  = rsqrtf(var + 1e-5f);
      if (ok) {
        #pragma unroll
        for (int ct = 0; ct < 8; ++ct)
          out_h[(size_t)n * H + ct * 16 + lr] = (v[ct] - mu) * rs * gma[ct] + bta[ct];
      }
    }
  }

  // x_new = x + coord_delta
  if (t < 128) {
    int n = nb + t;
    if (n < N) {
      #pragma unroll
      for (int c = 0; c < 3; ++c)
        out_x[(size_t)n * 3 + c] = x[(size_t)n * 3 + c] + cdelta[(size_t)n * 3 + c];
    }
  }
}

extern "C" void kernel_launch(void* const* d_in, const int* in_sizes, int n_in,
                              void* d_out, int out_size, void* d_ws, size_t ws_size,
                              hipStream_t stream) {
  const float* x     = (const float*)d_in[0];
  const float* h     = (const float*)d_in[1];
  const int*   ei    = (const int*)d_in[2];
  const float* ea    = (const float*)d_in[3];
  const float* Wm1   = (const float*)d_in[4];
  const float* bm1   = (const float*)d_in[5];
  const float* Wm2   = (const float*)d_in[6];
  const float* bm2   = (const float*)d_in[7];
  const float* Wn1   = (const float*)d_in[8];
  const float* bn1   = (const float*)d_in[9];
  const float* Wn2   = (const float*)d_in[10];
  const float* bn2   = (const float*)d_in[11];
  const float* Wc1   = (const float*)d_in[12];
  const float* bc1   = (const float*)d_in[13];
  const float* Wc2   = (const float*)d_in[14];
  const float* bc2   = (const float*)d_in[15];
  const float* gamma = (const float*)d_in[16];
  const float* beta  = (const float*)d_in[17];

  const int N = in_sizes[0] / 3;
  const int E = in_sizes[2] / 2;

  float* agg    = (float*)d_ws;                                     // N*H f32
  float* cdelta = agg + (size_t)N * H;                              // N*3 f32
  unsigned short* hbf   = (unsigned short*)(cdelta + (size_t)N * 3);// N*H bf16
  unsigned short* aggbf = hbf + (size_t)N * H;                      // N*H bf16
  unsigned short* wpre  = aggbf + (size_t)N * H;                    // NTILE*8192 bf16
  float* out_x  = (float*)d_out;
  float* out_h  = out_x + (size_t)N * 3;

  hipMemsetAsync(d_ws, 0, (size_t)(N * H + N * 3) * sizeof(float), stream);

  egnn_wconv<<<(NTILE * 1024 + 255) / 256, 256, 0, stream>>>(Wm1, Wm2, Wc1, Wn1, Wn2, wpre);
  egnn_hconv<<<(N * 16 + 255) / 256, 256, 0, stream>>>(h, hbf, N * 16);

  const int eblocks = (E + 127) / 128;
  egnn_edge_mfma<<<eblocks, 256, 0, stream>>>(
      x, ei, ea, hbf, wpre, bm1, bm2, bc1, Wc2, bc2, agg, cdelta, E);

  egnn_hconv<<<(N * 16 + 255) / 256, 256, 0, stream>>>(agg, aggbf, N * 16);

  const int nblocks = (N + 127) / 128;
  egnn_node_mfma<<<nblocks, 256, 0, stream>>>(
      x, h, hbf, aggbf, wpre, bn1, bn2, gamma, beta, cdelta, out_x, out_h, N);
}